// Round 8
// baseline (77.757 us; speedup 1.0000x reference)
//
#include <hip/hip_runtime.h>
#include <hip/hip_bf16.h>

#define NBATCH 4
#define NNODE  20000
#define NF     128
#define NK     16
#define NROWS  (NBATCH * NNODE)   // 80000
#define NBLK   1250               // 64 rows per block
#define WTF_BYTES 65536           // 16t x 4s x 64lane x 16B fragment-permuted weights
#define BIAS_OFF  WTF_BYTES
#define S_OFF     (WTF_BYTES + 1024)          // bf16 s = x*Ws + b   (20.48 MB)
#define Y_OFF     (S_OFF + NROWS * NF * 2)    // fp8  y = x*Wn       (10.24 MB)

typedef __attribute__((ext_vector_type(8))) short bf16x8_t;
typedef __attribute__((ext_vector_type(4))) float f32x4_t;
typedef __attribute__((ext_vector_type(2))) float f32x2_t;

__device__ __forceinline__ unsigned int f2bf(float f) {
  unsigned int u = __float_as_uint(f);
  u += 0x7fffu + ((u >> 16) & 1u);
  return u >> 16;
}

__device__ __forceinline__ int xcd_swz(int orig) {
  // bijective XCD-chunked swizzle for nwg=1250: q=156, r=2
  const int xcd = orig & 7, i = orig >> 3;
  const int q = NBLK / 8, r = NBLK % 8;
  return (xcd < r ? xcd * (q + 1) : r * (q + 1) + (xcd - r) * q) + i;
}

// ---------------- K1: weight fragments + bias sum ------------------------
__global__ __launch_bounds__(256) void sage_wprep(
    const float* __restrict__ Ws, const float* __restrict__ bs,
    const float* __restrict__ Wn, const float* __restrict__ bn,
    unsigned char* __restrict__ ws)
{
  const int bid = blockIdx.x, tid = threadIdx.x;
  if (bid == 16) {
    if (tid < NF) ((float*)(ws + BIAS_OFF))[tid] = bs[tid] + bn[tid];
    return;
  }
  const int ft = bid * 256 + tid;       // 0..4095
  const int gc = ft >> 8;               // col tile 0..15
  const int s  = (ft >> 6) & 3;         // k-step 0..3
  const int l  = ft & 63;
  const int colg = gc * 16 + (l & 15);  // 0..255 (stacked N)
  const int k0 = s * 32 + ((l >> 4) << 3);
  const float* W = (colg < NF) ? Ws : Wn;
  const int col = (colg < NF) ? colg : colg - NF;
  unsigned int w[4];
#pragma unroll
  for (int jj = 0; jj < 4; ++jj) {
    const float va = W[(k0 + 2 * jj) * NF + col];
    const float vb = W[(k0 + 2 * jj + 1) * NF + col];
    w[jj] = f2bf(va) | (f2bf(vb) << 16);
  }
  *reinterpret_cast<uint4*>(ws + (size_t)ft * 16) = make_uint4(w[0], w[1], w[2], w[3]);
}

// ---------------- K2: dense GEMM (operand-swapped MFMA) ------------------
// acc[t] = mfma(W_frag[t], x_frag)  ->  D[wcol][xrow]:
//   lane&15 = x-row, (lane>>4)*4+reg = wcol within tile t
// => each lane owns row (row0+fl), 4 CONSECUTIVE cols per tile: packed stores.
__global__ __launch_bounds__(256) void sage_gemm(
    const float* __restrict__ x, unsigned char* __restrict__ ws)
{
  const int tid = threadIdx.x, lane = tid & 63, wid = tid >> 6;
  const int bid = xcd_swz(blockIdx.x);
  const int row0 = bid * 64 + wid * 16;
  const int fl = lane & 15, q = lane >> 4;

  // x fragments: 16 rows x K=128, straight from f32 x, inline bf16 convert
  bf16x8_t afr[4];
  const float* xr = x + (size_t)(row0 + fl) * NF + q * 8;
#pragma unroll
  for (int s = 0; s < 4; ++s) {
    const float4 v0 = *reinterpret_cast<const float4*>(xr + s * 32);
    const float4 v1 = *reinterpret_cast<const float4*>(xr + s * 32 + 4);
    union { unsigned int u[4]; bf16x8_t v; } r;
    r.u[0] = f2bf(v0.x) | (f2bf(v0.y) << 16);
    r.u[1] = f2bf(v0.z) | (f2bf(v0.w) << 16);
    r.u[2] = f2bf(v1.x) | (f2bf(v1.y) << 16);
    r.u[3] = f2bf(v1.z) | (f2bf(v1.w) << 16);
    afr[s] = r.v;
  }

  f32x4_t acc[16];
#pragma unroll
  for (int t = 0; t < 16; ++t) acc[t] = (f32x4_t){0.f, 0.f, 0.f, 0.f};

  const bf16x8_t* wtf = reinterpret_cast<const bf16x8_t*>(ws);
#pragma unroll
  for (int t = 0; t < 16; ++t) {
#pragma unroll
    for (int s = 0; s < 4; ++s) {
      acc[t] = __builtin_amdgcn_mfma_f32_16x16x32_bf16(
          wtf[(t * 4 + s) * 64 + lane], afr[s], acc[t], 0, 0, 0);
    }
  }

  const float* bias = reinterpret_cast<const float*>(ws + BIAS_OFF);
  unsigned short* sp = reinterpret_cast<unsigned short*>(ws + S_OFF);
  unsigned char*  yp = ws + Y_OFF;
  const int myrow = row0 + fl;

  // s-half: tiles 0..7 -> cols t*16 + q*4 + (0..3) of x*Ws, +bias, bf16
#pragma unroll
  for (int t = 0; t < 8; ++t) {
    const int c4 = t * 16 + q * 4;
    const float4 b = *reinterpret_cast<const float4*>(bias + c4);
    uint2 p;
    p.x = f2bf(acc[t][0] + b.x) | (f2bf(acc[t][1] + b.y) << 16);
    p.y = f2bf(acc[t][2] + b.z) | (f2bf(acc[t][3] + b.w) << 16);
    *reinterpret_cast<uint2*>(sp + (size_t)myrow * NF + c4) = p;
  }
  // y-half: tiles 8..15 -> cols (t-8)*16 + q*4 + (0..3) of x*Wn, fp8 e4m3
#pragma unroll
  for (int t = 8; t < 16; ++t) {
    const int c4 = (t - 8) * 16 + q * 4;
    int w8 = __builtin_amdgcn_cvt_pk_fp8_f32(acc[t][0], acc[t][1], 0, false);
    w8 = __builtin_amdgcn_cvt_pk_fp8_f32(acc[t][2], acc[t][3], w8, true);
    *reinterpret_cast<unsigned int*>(yp + (size_t)myrow * NF + c4) =
        (unsigned int)w8;
  }
}

// ---------------- K3: out = relu(s + mean_k y[idx_k]) --------------------
__global__ __launch_bounds__(256) void sage_finish(
    const unsigned char* __restrict__ ws, const int* __restrict__ adj,
    float* __restrict__ out)
{
  const int tid = threadIdx.x, lane = tid & 63, wid = tid >> 6;
  const int bid = xcd_swz(blockIdx.x);
  const int rg = lane >> 4, fl = lane & 15;   // 4 rows/wave, 16 lanes/row

  const unsigned short* sp = reinterpret_cast<const unsigned short*>(ws + S_OFF);
  const unsigned char*  yp = ws + Y_OFF;

#pragma unroll
  for (int it = 0; it < 4; ++it) {
    const int row = bid * 64 + wid * 16 + it * 4 + rg;
    const int b = row / NNODE;
    const unsigned char* yb = yp + (size_t)b * NNODE * NF + fl * 8;
    const int4* a4 = reinterpret_cast<const int4*>(adj + (size_t)row * NK);
    const int4 t0 = a4[0], t1 = a4[1], t2 = a4[2], t3 = a4[3];
    const int idx[16] = {t0.x, t0.y, t0.z, t0.w, t1.x, t1.y, t1.z, t1.w,
                         t2.x, t2.y, t2.z, t2.w, t3.x, t3.y, t3.z, t3.w};

    const uint4 sv = *reinterpret_cast<const uint4*>(sp + (size_t)row * NF + fl * 8);

    float a[8];
#pragma unroll
    for (int e = 0; e < 8; ++e) a[e] = 0.f;

#define ACC2(word, base)                                                   \
    {                                                                      \
      f32x2_t lo = __builtin_amdgcn_cvt_pk_f32_fp8((word), false);         \
      f32x2_t hi = __builtin_amdgcn_cvt_pk_f32_fp8((word), true);          \
      a[(base) + 0] += lo[0]; a[(base) + 1] += lo[1];                      \
      a[(base) + 2] += hi[0]; a[(base) + 3] += hi[1];                      \
    }
#pragma unroll
    for (int g = 0; g < 4; ++g) {
      uint2 v0 = *reinterpret_cast<const uint2*>(yb + (size_t)idx[g * 4 + 0] * NF);
      uint2 v1 = *reinterpret_cast<const uint2*>(yb + (size_t)idx[g * 4 + 1] * NF);
      uint2 v2 = *reinterpret_cast<const uint2*>(yb + (size_t)idx[g * 4 + 2] * NF);
      uint2 v3 = *reinterpret_cast<const uint2*>(yb + (size_t)idx[g * 4 + 3] * NF);
      ACC2(v0.x, 0) ACC2(v0.y, 4)
      ACC2(v1.x, 0) ACC2(v1.y, 4)
      ACC2(v2.x, 0) ACC2(v2.y, 4)
      ACC2(v3.x, 0) ACC2(v3.y, 4)
    }
#undef ACC2

    float se[8];
    se[0] = __uint_as_float(sv.x << 16); se[1] = __uint_as_float(sv.x & 0xffff0000u);
    se[2] = __uint_as_float(sv.y << 16); se[3] = __uint_as_float(sv.y & 0xffff0000u);
    se[4] = __uint_as_float(sv.z << 16); se[5] = __uint_as_float(sv.z & 0xffff0000u);
    se[6] = __uint_as_float(sv.w << 16); se[7] = __uint_as_float(sv.w & 0xffff0000u);

    const float sc = 1.f / 16.f;
    float4 o0, o1;
    o0.x = fmaxf(se[0] + a[0] * sc, 0.f);
    o0.y = fmaxf(se[1] + a[1] * sc, 0.f);
    o0.z = fmaxf(se[2] + a[2] * sc, 0.f);
    o0.w = fmaxf(se[3] + a[3] * sc, 0.f);
    o1.x = fmaxf(se[4] + a[4] * sc, 0.f);
    o1.y = fmaxf(se[5] + a[5] * sc, 0.f);
    o1.z = fmaxf(se[6] + a[6] * sc, 0.f);
    o1.w = fmaxf(se[7] + a[7] * sc, 0.f);
    float* op = out + (size_t)row * NF + fl * 8;
    *reinterpret_cast<float4*>(op)     = o0;
    *reinterpret_cast<float4*>(op + 4) = o1;
  }
}

extern "C" void kernel_launch(void* const* d_in, const int* in_sizes, int n_in,
                              void* d_out, int out_size, void* d_ws, size_t ws_size,
                              hipStream_t stream) {
  const float* x     = (const float*)d_in[0];
  const int*   adj   = (const int*)d_in[1];
  const float* Wself = (const float*)d_in[2];
  const float* bself = (const float*)d_in[3];
  const float* Wnei  = (const float*)d_in[4];
  const float* bnei  = (const float*)d_in[5];
  float* out = (float*)d_out;
  unsigned char* ws = (unsigned char*)d_ws;

  hipLaunchKernelGGL(sage_wprep, dim3(17), dim3(256), 0, stream,
                     Wself, bself, Wnei, bnei, ws);
  hipLaunchKernelGGL(sage_gemm, dim3(NBLK), dim3(256), 0, stream, x, ws);
  hipLaunchKernelGGL(sage_finish, dim3(NBLK), dim3(256), 0, stream,
                     ws, adj, out);
}

// Round 9
// 60.972 us; speedup vs baseline: 1.2753x; 1.2753x over previous
//
#include <hip/hip_runtime.h>
#include <hip/hip_bf16.h>

#define NBATCH 4
#define NNODE  20000
#define NF     128
#define NK     16
#define NROWS  (NBATCH * NNODE)   // 80000
#define NBLK   1250               // 64 rows per block (4 waves x 16 rows)
#define WTF_BYTES 65536           // 8t x 8s x 64lane x 16B stacked-K weight frags
#define BIAS_OFF  WTF_BYTES
#define Y_OFF     (WTF_BYTES + 1024)   // fp8 x copy, fragment-interleaved (10.24 MB)

typedef __attribute__((ext_vector_type(8))) short bf16x8_t;
typedef __attribute__((ext_vector_type(4))) float f32x4_t;
typedef __attribute__((ext_vector_type(2))) float f32x2_t;

__device__ __forceinline__ unsigned int f2bf(float f) {
  unsigned int u = __float_as_uint(f);
  u += 0x7fffu + ((u >> 16) & 1u);
  return u >> 16;
}

__device__ __forceinline__ int xcd_swz(int orig) {
  // bijective XCD-chunked swizzle for nwg=1250: q=156, r=2
  const int xcd = orig & 7, i = orig >> 3;
  const int q = NBLK / 8, r = NBLK % 8;
  return (xcd < r ? xcd * (q + 1) : r * (q + 1) + (xcd - r) * q) + i;
}

// ---------------- K1: weight fragments (K=256 stacked) + bias sum --------
__global__ __launch_bounds__(256) void sage_wprep(
    const float* __restrict__ Ws, const float* __restrict__ bs,
    const float* __restrict__ Wn, const float* __restrict__ bn,
    unsigned char* __restrict__ ws)
{
  const int bid = blockIdx.x, tid = threadIdx.x;
  if (bid == 16) {
    if (tid < NF) ((float*)(ws + BIAS_OFF))[tid] = bs[tid] + bn[tid];
    return;
  }
  const int ft = bid * 256 + tid;       // 0..4095
  const int c = ft >> 9;                // out-col tile 0..7
  const int s = (ft >> 6) & 7;          // k-step 0..7 (K=256)
  const int l = ft & 63;
  const int col = c * 16 + (l & 15);
  const int k0 = s * 32 + ((l >> 4) << 3);
  unsigned int w[4];
#pragma unroll
  for (int jj = 0; jj < 4; ++jj) {
    const int ka = k0 + 2 * jj, kb = k0 + 2 * jj + 1;
    const float va = (ka < NF) ? Ws[ka * NF + col] : Wn[(ka - NF) * NF + col];
    const float vb = (kb < NF) ? Ws[kb * NF + col] : Wn[(kb - NF) * NF + col];
    w[jj] = f2bf(va) | (f2bf(vb) << 16);
  }
  *reinterpret_cast<uint4*>(ws + (size_t)ft * 16) = make_uint4(w[0], w[1], w[2], w[3]);
}

// ---------------- K2: fp8 x copy, fragment-interleaved -------------------
// feature f = s'*32 + q*8 + j  ->  byte pos = q*32 + s'*8 + j
__global__ __launch_bounds__(256) void sage_prep8(
    const float* __restrict__ x, unsigned char* __restrict__ ws)
{
  unsigned char* yp = ws + Y_OFF;
  const int total = NROWS * 32;   // uint (4-feature) chunks
  for (int c = blockIdx.x * 256 + threadIdx.x; c < total; c += 2048 * 256) {
    const int r = c >> 5;
    const int f = (c & 31) * 4;
    const float4 v = *reinterpret_cast<const float4*>(x + (size_t)r * NF + f);
    int p8 = __builtin_amdgcn_cvt_pk_fp8_f32(v.x, v.y, 0, false);
    p8 = __builtin_amdgcn_cvt_pk_fp8_f32(v.z, v.w, p8, true);
    const int q = (f >> 3) & 3, sp = f >> 5, j = f & 7;
    *reinterpret_cast<unsigned int*>(
        yp + (size_t)r * NF + q * 32 + sp * 8 + j) = (unsigned int)p8;
  }
}

// ---------------- K3: fused gather + stacked-K GEMM, no LDS, no barriers -
__global__ __launch_bounds__(256) void sage_fused(
    const float* __restrict__ x, const unsigned char* __restrict__ ws,
    const int* __restrict__ adj, float* __restrict__ out)
{
  const int tid = threadIdx.x, lane = tid & 63, wid = tid >> 6;
  const int bid = xcd_swz(blockIdx.x);
  const int fl = lane & 15, q = lane >> 4;
  const int myrow = bid * 64 + wid * 16 + fl;

  // ---- B-fragments, x-half (k=0..127): 8 consecutive f32 per k-step
  bf16x8_t bx[4];
  {
    const float* xr = x + (size_t)myrow * NF + q * 8;
#pragma unroll
    for (int s = 0; s < 4; ++s) {
      const float4 v0 = *reinterpret_cast<const float4*>(xr + s * 32);
      const float4 v1 = *reinterpret_cast<const float4*>(xr + s * 32 + 4);
      union { unsigned int u[4]; bf16x8_t v; } r;
      r.u[0] = f2bf(v0.x) | (f2bf(v0.y) << 16);
      r.u[1] = f2bf(v0.z) | (f2bf(v0.w) << 16);
      r.u[2] = f2bf(v1.x) | (f2bf(v1.y) << 16);
      r.u[3] = f2bf(v1.z) | (f2bf(v1.w) << 16);
      bx[s] = r.v;
    }
  }

  // ---- gather + mean into B-fragments, m-half (k=128..255)
  bf16x8_t bm[4];
  {
    const int b = myrow / NNODE;
    const unsigned char* yb =
        ws + Y_OFF + (size_t)b * NNODE * NF + q * 32;  // lane's 32B per node
    const int4* a4 = reinterpret_cast<const int4*>(adj + (size_t)myrow * NK);
    const int4 t0 = a4[0], t1 = a4[1], t2 = a4[2], t3 = a4[3];
    const int idx[16] = {t0.x, t0.y, t0.z, t0.w, t1.x, t1.y, t1.z, t1.w,
                         t2.x, t2.y, t2.z, t2.w, t3.x, t3.y, t3.z, t3.w};

    f32x2_t g[16];
#pragma unroll
    for (int e = 0; e < 16; ++e) g[e] = (f32x2_t){0.f, 0.f};

#define ACCW(word, base)                                                   \
    {                                                                      \
      g[(base)]     += __builtin_amdgcn_cvt_pk_f32_fp8((word), false);     \
      g[(base) + 1] += __builtin_amdgcn_cvt_pk_f32_fp8((word), true);      \
    }
#pragma unroll
    for (int n = 0; n < 16; n += 4) {   // 4 neighbors per batch in flight
      uint4 u0a = *reinterpret_cast<const uint4*>(yb + (size_t)idx[n + 0] * NF);
      uint4 u0b = *reinterpret_cast<const uint4*>(yb + (size_t)idx[n + 0] * NF + 16);
      uint4 u1a = *reinterpret_cast<const uint4*>(yb + (size_t)idx[n + 1] * NF);
      uint4 u1b = *reinterpret_cast<const uint4*>(yb + (size_t)idx[n + 1] * NF + 16);
      uint4 u2a = *reinterpret_cast<const uint4*>(yb + (size_t)idx[n + 2] * NF);
      uint4 u2b = *reinterpret_cast<const uint4*>(yb + (size_t)idx[n + 2] * NF + 16);
      uint4 u3a = *reinterpret_cast<const uint4*>(yb + (size_t)idx[n + 3] * NF);
      uint4 u3b = *reinterpret_cast<const uint4*>(yb + (size_t)idx[n + 3] * NF + 16);
      ACCW(u0a.x, 0)  ACCW(u0a.y, 2)  ACCW(u0a.z, 4)  ACCW(u0a.w, 6)
      ACCW(u0b.x, 8)  ACCW(u0b.y, 10) ACCW(u0b.z, 12) ACCW(u0b.w, 14)
      ACCW(u1a.x, 0)  ACCW(u1a.y, 2)  ACCW(u1a.z, 4)  ACCW(u1a.w, 6)
      ACCW(u1b.x, 8)  ACCW(u1b.y, 10) ACCW(u1b.z, 12) ACCW(u1b.w, 14)
      ACCW(u2a.x, 0)  ACCW(u2a.y, 2)  ACCW(u2a.z, 4)  ACCW(u2a.w, 6)
      ACCW(u2b.x, 8)  ACCW(u2b.y, 10) ACCW(u2b.z, 12) ACCW(u2b.w, 14)
      ACCW(u3a.x, 0)  ACCW(u3a.y, 2)  ACCW(u3a.z, 4)  ACCW(u3a.w, 6)
      ACCW(u3b.x, 8)  ACCW(u3b.y, 10) ACCW(u3b.z, 12) ACCW(u3b.w, 14)
    }
#undef ACCW

    const float sc = 1.f / 16.f;
#pragma unroll
    for (int sp = 0; sp < 4; ++sp) {
      union { unsigned int u[4]; bf16x8_t v; } r;
#pragma unroll
      for (int e = 0; e < 4; ++e) {
        const f32x2_t a = g[sp * 4 + e];
        r.u[e] = f2bf(a[0] * sc) | (f2bf(a[1] * sc) << 16);
      }
      bm[sp] = r.v;
    }
  }

  // ---- MFMA: A = stacked weights (64KB table, L1/L2-hot), B = [x|m]
  f32x4_t acc[8];
#pragma unroll
  for (int t = 0; t < 8; ++t) acc[t] = (f32x4_t){0.f, 0.f, 0.f, 0.f};

  const bf16x8_t* wtf = reinterpret_cast<const bf16x8_t*>(ws);
#pragma unroll
  for (int t = 0; t < 8; ++t) {
#pragma unroll
    for (int s = 0; s < 4; ++s)
      acc[t] = __builtin_amdgcn_mfma_f32_16x16x32_bf16(
          wtf[(t * 8 + s) * 64 + lane], bx[s], acc[t], 0, 0, 0);
#pragma unroll
    for (int s = 4; s < 8; ++s)
      acc[t] = __builtin_amdgcn_mfma_f32_16x16x32_bf16(
          wtf[(t * 8 + s) * 64 + lane], bm[s - 4], acc[t], 0, 0, 0);
  }

  // ---- epilogue: D[col=myrow(lane&15), row=q*4+reg] -> packed float4
  const float* bias = reinterpret_cast<const float*>(ws + BIAS_OFF);
  float* op = out + (size_t)myrow * NF;
#pragma unroll
  for (int t = 0; t < 8; ++t) {
    const int c4 = t * 16 + q * 4;
    const float4 b = *reinterpret_cast<const float4*>(bias + c4);
    float4 o;
    o.x = fmaxf(acc[t][0] + b.x, 0.f);
    o.y = fmaxf(acc[t][1] + b.y, 0.f);
    o.z = fmaxf(acc[t][2] + b.z, 0.f);
    o.w = fmaxf(acc[t][3] + b.w, 0.f);
    *reinterpret_cast<float4*>(op + c4) = o;
  }
}

extern "C" void kernel_launch(void* const* d_in, const int* in_sizes, int n_in,
                              void* d_out, int out_size, void* d_ws, size_t ws_size,
                              hipStream_t stream) {
  const float* x     = (const float*)d_in[0];
  const int*   adj   = (const int*)d_in[1];
  const float* Wself = (const float*)d_in[2];
  const float* bself = (const float*)d_in[3];
  const float* Wnei  = (const float*)d_in[4];
  const float* bnei  = (const float*)d_in[5];
  float* out = (float*)d_out;
  unsigned char* ws = (unsigned char*)d_ws;

  hipLaunchKernelGGL(sage_wprep, dim3(17), dim3(256), 0, stream,
                     Wself, bself, Wnei, bnei, ws);
  hipLaunchKernelGGL(sage_prep8, dim3(2048), dim3(256), 0, stream, x, ws);
  hipLaunchKernelGGL(sage_fused, dim3(NBLK), dim3(256), 0, stream,
                     x, ws, adj, out);
}

// Round 10
// 52.217 us; speedup vs baseline: 1.4891x; 1.1677x over previous
//
#include <hip/hip_runtime.h>
#include <hip/hip_bf16.h>

#define NBATCH 4
#define NNODE  20000
#define NF     128
#define NK     16
#define NROWS  (NBATCH * NNODE)   // 80000
#define NBLK_G 1250               // gemm blocks, 64 rows each
#define NBLK_F 5000               // finish blocks, 16 rows each
#define WTF_BYTES 65536           // 16t x 4s x 64lane x 16B weight frags (N=256 stacked)
#define BIAS_OFF  WTF_BYTES
#define S_OFF     (WTF_BYTES + 1024)          // bf16 s = x*Ws + b  (20.48 MB)
#define Y_OFF     (S_OFF + NROWS * NF * 2)    // fp8  y = x*Wn      (10.24 MB)

typedef __attribute__((ext_vector_type(8))) short bf16x8_t;
typedef __attribute__((ext_vector_type(4))) float f32x4_t;
typedef __attribute__((ext_vector_type(2))) float f32x2_t;

__device__ __forceinline__ unsigned int f2bf(float f) {
  unsigned int u = __float_as_uint(f);
  u += 0x7fffu + ((u >> 16) & 1u);
  return u >> 16;
}

__device__ __forceinline__ int xcd_swz_g(int orig) {
  // bijective XCD-chunked swizzle, nwg=1250: q=156, r=2
  const int xcd = orig & 7, i = orig >> 3;
  const int q = NBLK_G / 8, r = NBLK_G % 8;
  return (xcd < r ? xcd * (q + 1) : r * (q + 1) + (xcd - r) * q) + i;
}

__device__ __forceinline__ int xcd_swz_f(int orig) {
  // nwg=5000 divisible by 8: simple chunked form
  return (orig & 7) * (NBLK_F / 8) + (orig >> 3);
}

__device__ __forceinline__ void stage16(const void* g, void* l) {
  __builtin_amdgcn_global_load_lds(
      (const __attribute__((address_space(1))) unsigned int*)g,
      (__attribute__((address_space(3))) unsigned int*)l, 16, 0, 0);
}

// ---------------- K1: weight fragments (N=256 stacked, K=128) + bias -----
__global__ __launch_bounds__(256) void sage_wprep(
    const float* __restrict__ Ws, const float* __restrict__ bs,
    const float* __restrict__ Wn, const float* __restrict__ bn,
    unsigned char* __restrict__ ws)
{
  const int bid = blockIdx.x, tid = threadIdx.x;
  if (bid == 16) {
    if (tid < NF) ((float*)(ws + BIAS_OFF))[tid] = bs[tid] + bn[tid];
    return;
  }
  const int ft = bid * 256 + tid;       // 0..4095
  const int gc = ft >> 8;               // col tile 0..15
  const int s  = (ft >> 6) & 3;         // k-step 0..3 (K=128)
  const int l  = ft & 63;
  const int colg = gc * 16 + (l & 15);  // 0..255 stacked N
  const int k0 = s * 32 + ((l >> 4) << 3);
  const float* W = (colg < NF) ? Ws : Wn;
  const int col = (colg < NF) ? colg : colg - NF;
  unsigned int w[4];
#pragma unroll
  for (int jj = 0; jj < 4; ++jj) {
    const float va = W[(k0 + 2 * jj) * NF + col];
    const float vb = W[(k0 + 2 * jj + 1) * NF + col];
    w[jj] = f2bf(va) | (f2bf(vb) << 16);
  }
  *reinterpret_cast<uint4*>(ws + (size_t)ft * 16) = make_uint4(w[0], w[1], w[2], w[3]);
}

// ---------------- K2: dense GEMM, weights via LDS, two 32KB phases -------
// operand-swapped: acc[t] = mfma(Wfrag, xfrag) -> lane owns row (lane&15),
// 4 consecutive cols (q*4+reg) per tile -> packed stores.
__global__ __launch_bounds__(256) void sage_gemm(
    const float* __restrict__ x, unsigned char* __restrict__ ws)
{
  __shared__ __align__(16) unsigned char sW[32768];
  const int tid = threadIdx.x, lane = tid & 63, wid = tid >> 6;
  const int bid = xcd_swz_g(blockIdx.x);
  const int fl = lane & 15, q = lane >> 4;
  const int myrow = bid * 64 + wid * 16 + fl;

  // issue x loads first (oldest in vmcnt FIFO -> wait leaves staging in flight)
  const float* xr = x + (size_t)myrow * NF + q * 8;
  float4 xv[8];
#pragma unroll
  for (int s = 0; s < 4; ++s) {
    xv[2 * s]     = *reinterpret_cast<const float4*>(xr + s * 32);
    xv[2 * s + 1] = *reinterpret_cast<const float4*>(xr + s * 32 + 4);
  }
  // stage s-half weight table (32KB): 8 chunks of 1KB per wave
#pragma unroll
  for (int i = 0; i < 8; ++i) {
    const int c0 = i * 256 + wid * 64;
    stage16(ws + (size_t)(c0 + lane) * 16, sW + (size_t)c0 * 16);
  }
  __builtin_amdgcn_sched_barrier(0);

  // convert x to bf16 fragments (waits only on x loads, staging stays in flight)
  bf16x8_t bx[4];
#pragma unroll
  for (int s = 0; s < 4; ++s) {
    union { unsigned int u[4]; bf16x8_t v; } r;
    r.u[0] = f2bf(xv[2 * s].x) | (f2bf(xv[2 * s].y) << 16);
    r.u[1] = f2bf(xv[2 * s].z) | (f2bf(xv[2 * s].w) << 16);
    r.u[2] = f2bf(xv[2 * s + 1].x) | (f2bf(xv[2 * s + 1].y) << 16);
    r.u[3] = f2bf(xv[2 * s + 1].z) | (f2bf(xv[2 * s + 1].w) << 16);
    bx[s] = r.v;
  }
  __syncthreads();   // staging complete

  const bf16x8_t* sWf = reinterpret_cast<const bf16x8_t*>(sW);

  // ---- phase 1: s-half (tiles 0..7), A-frags via ds_read_b128
  f32x4_t acc[8];
#pragma unroll
  for (int t = 0; t < 8; ++t) acc[t] = (f32x4_t){0.f, 0.f, 0.f, 0.f};
#pragma unroll
  for (int t = 0; t < 8; ++t)
#pragma unroll
    for (int s = 0; s < 4; ++s)
      acc[t] = __builtin_amdgcn_mfma_f32_16x16x32_bf16(
          sWf[(t * 4 + s) * 64 + lane], bx[s], acc[t], 0, 0, 0);

  const float* bias = reinterpret_cast<const float*>(ws + BIAS_OFF);
  unsigned short* sp = reinterpret_cast<unsigned short*>(ws + S_OFF);
#pragma unroll
  for (int t = 0; t < 8; ++t) {
    const int c4 = t * 16 + q * 4;
    const float4 b = *reinterpret_cast<const float4*>(bias + c4);
    uint2 p;
    p.x = f2bf(acc[t][0] + b.x) | (f2bf(acc[t][1] + b.y) << 16);
    p.y = f2bf(acc[t][2] + b.z) | (f2bf(acc[t][3] + b.w) << 16);
    *reinterpret_cast<uint2*>(sp + (size_t)myrow * NF + c4) = p;
  }

  __syncthreads();   // all waves done reading sW before overwrite
  // ---- stage y-half weight table (tiles 8..15)
#pragma unroll
  for (int i = 0; i < 8; ++i) {
    const int c0 = i * 256 + wid * 64;
    stage16(ws + 32768 + (size_t)(c0 + lane) * 16, sW + (size_t)c0 * 16);
  }
  __syncthreads();   // staging complete

  // ---- phase 2: y-half
#pragma unroll
  for (int t = 0; t < 8; ++t) acc[t] = (f32x4_t){0.f, 0.f, 0.f, 0.f};
#pragma unroll
  for (int t = 0; t < 8; ++t)
#pragma unroll
    for (int s = 0; s < 4; ++s)
      acc[t] = __builtin_amdgcn_mfma_f32_16x16x32_bf16(
          sWf[(t * 4 + s) * 64 + lane], bx[s], acc[t], 0, 0, 0);

  unsigned char* yp = ws + Y_OFF;
#pragma unroll
  for (int t = 0; t < 8; ++t) {
    const int c4 = t * 16 + q * 4;
    int w8 = __builtin_amdgcn_cvt_pk_fp8_f32(acc[t][0], acc[t][1], 0, false);
    w8 = __builtin_amdgcn_cvt_pk_fp8_f32(acc[t][2], acc[t][3], w8, true);
    *reinterpret_cast<unsigned int*>(yp + (size_t)myrow * NF + c4) =
        (unsigned int)w8;
  }
}

// ---------------- K3: out = relu(s + mean_k y[idx_k]), forced 16-deep MLP
__global__ __launch_bounds__(256) void sage_fin(
    const unsigned char* __restrict__ ws, const int* __restrict__ adj,
    float* __restrict__ out)
{
  const int tid = threadIdx.x, lane = tid & 63, wid = tid >> 6;
  const int bid = xcd_swz_f(blockIdx.x);
  const int rg = lane >> 4, fl = lane & 15;   // 4 rows/wave, 16 lanes/row
  const int row = bid * 16 + wid * 4 + rg;
  const int b = row / NNODE;

  const unsigned short* sp = reinterpret_cast<const unsigned short*>(ws + S_OFF);
  const unsigned char* yb = ws + Y_OFF + (size_t)b * NNODE * NF + fl * 8;

  const int4* a4 = reinterpret_cast<const int4*>(adj + (size_t)row * NK);
  const int4 t0 = a4[0], t1 = a4[1], t2 = a4[2], t3 = a4[3];
  const int idx[16] = {t0.x, t0.y, t0.z, t0.w, t1.x, t1.y, t1.z, t1.w,
                       t2.x, t2.y, t2.z, t2.w, t3.x, t3.y, t3.z, t3.w};

  const uint4 sv = *reinterpret_cast<const uint4*>(sp + (size_t)row * NF + fl * 8);

  uint2 v[16];
#pragma unroll
  for (int k = 0; k < 16; ++k)
    v[k] = *reinterpret_cast<const uint2*>(yb + (size_t)idx[k] * NF);
  __builtin_amdgcn_sched_barrier(0);   // pin: all 16 loads issue before use

  f32x2_t g0 = {0.f, 0.f}, g1 = {0.f, 0.f}, g2 = {0.f, 0.f}, g3 = {0.f, 0.f};
#pragma unroll
  for (int k = 0; k < 16; ++k) {
    g0 += __builtin_amdgcn_cvt_pk_f32_fp8(v[k].x, false);
    g1 += __builtin_amdgcn_cvt_pk_f32_fp8(v[k].x, true);
    g2 += __builtin_amdgcn_cvt_pk_f32_fp8(v[k].y, false);
    g3 += __builtin_amdgcn_cvt_pk_f32_fp8(v[k].y, true);
  }

  float se[8];
  se[0] = __uint_as_float(sv.x << 16); se[1] = __uint_as_float(sv.x & 0xffff0000u);
  se[2] = __uint_as_float(sv.y << 16); se[3] = __uint_as_float(sv.y & 0xffff0000u);
  se[4] = __uint_as_float(sv.z << 16); se[5] = __uint_as_float(sv.z & 0xffff0000u);
  se[6] = __uint_as_float(sv.w << 16); se[7] = __uint_as_float(sv.w & 0xffff0000u);

  const float sc = 1.f / 16.f;
  float4 o0, o1;
  o0.x = fmaxf(se[0] + g0[0] * sc, 0.f);
  o0.y = fmaxf(se[1] + g0[1] * sc, 0.f);
  o0.z = fmaxf(se[2] + g1[0] * sc, 0.f);
  o0.w = fmaxf(se[3] + g1[1] * sc, 0.f);
  o1.x = fmaxf(se[4] + g2[0] * sc, 0.f);
  o1.y = fmaxf(se[5] + g2[1] * sc, 0.f);
  o1.z = fmaxf(se[6] + g3[0] * sc, 0.f);
  o1.w = fmaxf(se[7] + g3[1] * sc, 0.f);
  float* op = out + (size_t)row * NF + fl * 8;
  *reinterpret_cast<float4*>(op)     = o0;
  *reinterpret_cast<float4*>(op + 4) = o1;
}

extern "C" void kernel_launch(void* const* d_in, const int* in_sizes, int n_in,
                              void* d_out, int out_size, void* d_ws, size_t ws_size,
                              hipStream_t stream) {
  const float* x     = (const float*)d_in[0];
  const int*   adj   = (const int*)d_in[1];
  const float* Wself = (const float*)d_in[2];
  const float* bself = (const float*)d_in[3];
  const float* Wnei  = (const float*)d_in[4];
  const float* bnei  = (const float*)d_in[5];
  float* out = (float*)d_out;
  unsigned char* ws = (unsigned char*)d_ws;

  hipLaunchKernelGGL(sage_wprep, dim3(17), dim3(256), 0, stream,
                     Wself, bself, Wnei, bnei, ws);
  hipLaunchKernelGGL(sage_gemm, dim3(NBLK_G), dim3(256), 0, stream, x, ws);
  hipLaunchKernelGGL(sage_fin, dim3(NBLK_F), dim3(256), 0, stream,
                     ws, adj, out);
}